// Round 15
// baseline (343.701 us; speedup 1.0000x reference)
//
#include <hip/hip_runtime.h>
#include <math.h>

// GIN forward, MI355X. Round 15 submission = round 14 fp8-h experiment,
// textually refreshed after two container-level infra failures (r8 playbook).
// Hot-path semantics identical to the r14 source.

#define NHID 128
#define NFEAT 256
#define NCLASS 40

typedef __bf16 bf16x8 __attribute__((ext_vector_type(8)));
typedef __bf16 bf16x4 __attribute__((ext_vector_type(4)));
typedef float floatx4 __attribute__((ext_vector_type(4)));

// ===========================================================================
// Hand-rolled OCP fp8 e4m3fn (no header/intrinsic dependency).
// encode: RNE-ish round, saturate at 448, correct subnormals (q * 2^-9).
// decode: exact.
// ===========================================================================
__device__ __forceinline__ unsigned int enc_e4m3(float x) {
    unsigned int bits = __float_as_uint(x);
    unsigned int sgn = (bits >> 24) & 0x80u;
    float mag = __uint_as_float(bits & 0x7fffffffu);
    if (mag > 448.f) mag = 448.f;
    unsigned int mb = __float_as_uint(mag);
    int ex = (int)((mb >> 23) & 255u) - 127;
    unsigned int code;
    if (ex < -6) {
        int q = (int)(mag * 512.f + 0.5f);  // value = q * 2^-9, q in [0,8]
        code = (unsigned int)q;             // q==8 becomes min-normal
    } else {
        unsigned int man = mb & 0x7fffffu;
        unsigned int rnd = 0x7ffffu + ((man >> 20) & 1u);
        man += rnd;
        if (man >> 23) { man = 0; ex += 1; } else man >>= 20;
        if (ex > 8) { ex = 8; man = 6; }    // saturate at 448
        code = ((unsigned int)(ex + 7) << 3) | man;
    }
    return code | sgn;
}

__device__ __forceinline__ float dec_e4m3(unsigned int code) {
    unsigned int sgn = (code & 0x80u) << 24;
    unsigned int ex = (code >> 3) & 15u;
    unsigned int man = code & 7u;
    float v = ex ? __uint_as_float(((ex + 120u) << 23) | (man << 20))
                 : (float)man * 0.001953125f;  // 2^-9
    return __uint_as_float(__float_as_uint(v) | sgn);
}

// accumulate 8 fp8 elements (one 8-byte chunk) into acc[0..7]
__device__ __forceinline__ void acc_fp8x8(uint2 u, float* acc) {
#pragma unroll
    for (int j = 0; j < 4; ++j) acc[j] += dec_e4m3((u.x >> (8 * j)) & 0xffu);
#pragma unroll
    for (int j = 0; j < 4; ++j) acc[4 + j] += dec_e4m3((u.y >> (8 * j)) & 0xffu);
}

// ===========================================================================
// CSR build via 2-level bucketed counting sort.
// Dispatch A: hist (blocks [0,eb4)) || weight transpose (blocks [eb4,eb4+320)).
// ===========================================================================
__global__ __launch_bounds__(256) void hist_transpose(
    const int* __restrict__ edst, int* __restrict__ bucket_counts, int E, int eb4,
    int nbuck,
    const float* __restrict__ Win, const float* __restrict__ Wmlps,
    __bf16* __restrict__ dInHi, __bf16* __restrict__ dMlHi) {
    __shared__ int lhist[256];
    int tid = threadIdx.x;
    int bid = blockIdx.x;
    if (bid < eb4) {
        lhist[tid] = 0;
        __syncthreads();
        int base = bid * 4096;
#pragma unroll
        for (int k = 0; k < 16; ++k) {
            int e = base + k * 256 + tid;
            if (e < E) atomicAdd(&lhist[edst[e] >> 8], 1);
        }
        __syncthreads();
        if (tid < nbuck && lhist[tid]) atomicAdd(&bucket_counts[tid], lhist[tid]);
    } else {
        const int TOT_IN = 128 * NFEAT;      // 32768
        const int TOT_ML = 3 * 128 * NHID;   // 49152
        int i = (bid - eb4) * 256 + tid;
        if (i < TOT_IN) {
            int n = i / NFEAT;
            int k = i - n * NFEAT;
            dInHi[i] = (__bf16)Win[(size_t)k * 128 + n];
        } else if (i < TOT_IN + TOT_ML) {
            int r = i - TOT_IN;
            int per = 128 * NHID;
            int layer = r / per;
            int rr = r - layer * per;
            int n = rr / NHID;
            int k = rr - n * NHID;
            dMlHi[r] = (__bf16)Wmlps[(size_t)layer * per + (size_t)k * 128 + n];
        }
    }
}

__global__ __launch_bounds__(256) void bucket_scan(const int* __restrict__ counts,
                                                   int* __restrict__ start,
                                                   int* __restrict__ cursor,
                                                   int* __restrict__ row_ptr,
                                                   int nbuck, int E, int N) {
    __shared__ int sbuf[256];
    int tid = threadIdx.x;
    int v = (tid < nbuck) ? counts[tid] : 0;
    sbuf[tid] = v;
    __syncthreads();
    for (int off = 1; off < 256; off <<= 1) {
        int t = (tid >= off) ? sbuf[tid - off] : 0;
        __syncthreads();
        sbuf[tid] += t;
        __syncthreads();
    }
    int excl = sbuf[tid] - v;
    if (tid < nbuck) { start[tid] = excl; cursor[tid] = excl; }
    if (tid == 0) { start[nbuck] = E; row_ptr[N] = E; }
}

__global__ __launch_bounds__(256) void bucket_scatter(const int* __restrict__ esrc,
                                                      const int* __restrict__ edst,
                                                      int* __restrict__ cursor,
                                                      unsigned int* __restrict__ bdata,
                                                      int E, int nbuck) {
    __shared__ int lhist[256];
    __shared__ int lbase[256];
    int tid = threadIdx.x;
    lhist[tid] = 0;
    __syncthreads();
    int base = blockIdx.x * 4096;
    unsigned int recs[16];
    short bks[16];
    short lofs[16];
#pragma unroll
    for (int k = 0; k < 16; ++k) {
        int e = base + k * 256 + tid;
        bks[k] = -1;
        if (e < E) {
            int d = edst[e];
            int s = esrc[e];
            int b = d >> 8;
            recs[k] = ((unsigned int)(d & 255) << 16) | (unsigned int)s;
            bks[k] = (short)b;
            lofs[k] = (short)atomicAdd(&lhist[b], 1);
        }
    }
    __syncthreads();
    if (tid < nbuck && lhist[tid]) lbase[tid] = atomicAdd(&cursor[tid], lhist[tid]);
    __syncthreads();
#pragma unroll
    for (int k = 0; k < 16; ++k) {
        if (bks[k] >= 0) bdata[lbase[bks[k]] + lofs[k]] = recs[k];
    }
}

// ===========================================================================
// Dispatch D: FINALIZE (blocks [0,nbuck)) || GEMM_IN (blocks [nbuck,..+gb)).
// gemm_in: 64 rows x 128 cols, K=256, W bf16 staged once (64KB), barrier-free
// k-loop, A = fp32 x with in-register hi/lo split (2 MFMA). h output = FP8.
// ===========================================================================
__global__ __launch_bounds__(256) void fin_gemmin64(
    const unsigned int* __restrict__ bdata, const int* __restrict__ start,
    int* __restrict__ row_ptr, int* __restrict__ srcs, int N, int nbuck,
    const float* __restrict__ Af,
    const __bf16* __restrict__ Wthi,
    const float* __restrict__ bias, unsigned char* __restrict__ Ofp8) {
    __shared__ __align__(16) char smem[65536];
    int tid = threadIdx.x;
    if ((int)blockIdx.x < nbuck) {
        int* hist = (int*)smem;
        int* cur  = (int*)(smem + 1024);
        int b = blockIdx.x;
        int s0 = start[b];
        int cnt = start[b + 1] - s0;
        hist[tid] = 0;
        __syncthreads();
        for (int i = tid; i < cnt; i += 256) atomicAdd(&hist[bdata[s0 + i] >> 16], 1);
        __syncthreads();
        int v0 = hist[tid];
        __syncthreads();
        for (int off = 1; off < 256; off <<= 1) {
            int t = (tid >= off) ? hist[tid - off] : 0;
            __syncthreads();
            hist[tid] += t;
            __syncthreads();
        }
        int excl = hist[tid] - v0;
        cur[tid] = excl;
        int node = b * 256 + tid;
        if (node < N) row_ptr[node] = s0 + excl;
        __syncthreads();
        for (int i = tid; i < cnt; i += 256) {
            unsigned int r = bdata[s0 + i];
            int p = atomicAdd(&cur[r >> 16], 1);
            srcs[s0 + p] = (int)(r & 0xffffu);
        }
        return;
    }
    // ---------------- gemm_in ----------------
    __bf16* sW = (__bf16*)smem;                  // 128 cols x 256 k = 64KB
    int bix = (int)blockIdx.x - nbuck;
    int row0 = bix * 64;
    int wave = tid >> 6;
    int l = tid & 63;
    int m16 = l & 15;
    int q = l >> 4;
    int garow = min(row0 + wave * 16 + m16, N - 1);

#pragma unroll
    for (int it = 0; it < 16; ++it) {
        int lin = it * 2048 + tid * 8;
        int wr = lin >> 8, k = lin & 255;
        int off = wr * 256 + (((k >> 3) ^ (wr & 7)) << 3);
        *(bf16x8*)(sW + off) = *(const bf16x8*)&Wthi[(size_t)wr * 256 + k];
    }
    __syncthreads();

    floatx4 acc[8];
#pragma unroll
    for (int t = 0; t < 8; ++t) acc[t] = (floatx4){0.f, 0.f, 0.f, 0.f};

#pragma unroll
    for (int fs = 0; fs < 8; ++fs) {
        int kk = fs * 32 + q * 8;
        float4 v0 = *(const float4*)&Af[(size_t)garow * 256 + kk];
        float4 v1 = *(const float4*)&Af[(size_t)garow * 256 + kk + 4];
        float sv[8] = {v0.x, v0.y, v0.z, v0.w, v1.x, v1.y, v1.z, v1.w};
        bf16x8 ahi, alo;
#pragma unroll
        for (int j = 0; j < 8; ++j) {
            __bf16 h = (__bf16)sv[j];
            ahi[j] = h;
            alo[j] = (__bf16)(sv[j] - (float)h);
        }
#pragma unroll
        for (int t = 0; t < 8; ++t) {
            int n = t * 16 + m16;
            int soff = n * 256 + (((kk >> 3) ^ (n & 7)) << 3);
            bf16x8 b = *(bf16x8*)(sW + soff);
            acc[t] = __builtin_amdgcn_mfma_f32_16x16x32_bf16(ahi, b, acc[t], 0, 0, 0);
            acc[t] = __builtin_amdgcn_mfma_f32_16x16x32_bf16(alo, b, acc[t], 0, 0, 0);
        }
    }

    // epilogue: reuse W LDS as 64x132 fp32 buffer; FP8 store
    __syncthreads();
    float* eps = (float*)smem;
#pragma unroll
    for (int t = 0; t < 8; ++t) {
        int col = t * 16 + m16;
        float bb = bias[col];
#pragma unroll
        for (int i = 0; i < 4; ++i) {
            int row = wave * 16 + q * 4 + i;
            eps[row * 132 + col] = fmaxf(acc[t][i] + bb, 0.f);
        }
    }
    __syncthreads();
#pragma unroll
    for (int it = 0; it < 8; ++it) {
        int lin = it * 1024 + tid * 4;
        int row = lin >> 7, col = lin & 127;
        int g = row0 + row;
        if (g < N) {
            float4 v = *(float4*)(eps + row * 132 + col);
            unsigned int p = enc_e4m3(v.x) | (enc_e4m3(v.y) << 8) |
                             (enc_e4m3(v.z) << 16) | (enc_e4m3(v.w) << 24);
            *(unsigned int*)&Ofp8[(size_t)g * 128 + col] = p;
        }
    }
}

// ===========================================================================
// Fused aggregate: sum = h[node] + sum_{src in CSR} h[src], h stored FP8
// (128 B/row). Output sum in bf16 (GEMM A-operand precision preserved).
// One wave/node; 16 lanes x 8B chunk; 16 edges (4 gathers) in flight.
// ===========================================================================
__global__ __launch_bounds__(256) void aggregate_fused(const unsigned char* __restrict__ hfp8,
                                                       const int* __restrict__ row_ptr,
                                                       const int* __restrict__ srcs,
                                                       __bf16* __restrict__ ohi, int N) {
    int tid = threadIdx.x;
    int node = blockIdx.x * 4 + (tid >> 6);
    if (node >= N) return;
    int lane = tid & 63;
    int g = lane >> 4;
    int c = lane & 15;   // 8B chunk (8 fp8 features)
    int beg = row_ptr[node];
    int end = row_ptr[node + 1];
    const uint2* hv = (const uint2*)hfp8;

    uint2 selfu = hv[(size_t)node * 16 + c];

    float a[8], b2[8];
#pragma unroll
    for (int j = 0; j < 8; ++j) { a[j] = 0.f; b2[j] = 0.f; }

    int i = beg;
    for (; i + 16 <= end; i += 16) {
        int s0 = __builtin_nontemporal_load(&srcs[i + g]);
        int s1 = __builtin_nontemporal_load(&srcs[i + 4 + g]);
        int s2 = __builtin_nontemporal_load(&srcs[i + 8 + g]);
        int s3 = __builtin_nontemporal_load(&srcs[i + 12 + g]);
        uint2 v0 = hv[(size_t)s0 * 16 + c];
        uint2 v1 = hv[(size_t)s1 * 16 + c];
        uint2 v2 = hv[(size_t)s2 * 16 + c];
        uint2 v3 = hv[(size_t)s3 * 16 + c];
        acc_fp8x8(v0, a);
        acc_fp8x8(v1, b2);
        acc_fp8x8(v2, a);
        acc_fp8x8(v3, b2);
    }
    for (; i + 8 <= end; i += 8) {
        int s0 = __builtin_nontemporal_load(&srcs[i + g]);
        int s1 = __builtin_nontemporal_load(&srcs[i + 4 + g]);
        uint2 v0 = hv[(size_t)s0 * 16 + c];
        uint2 v1 = hv[(size_t)s1 * 16 + c];
        acc_fp8x8(v0, a);
        acc_fp8x8(v1, b2);
    }
    for (; i < end; i += 4) {
        if (i + g < end) {
            int s = __builtin_nontemporal_load(&srcs[i + g]);
            uint2 v = hv[(size_t)s * 16 + c];
            acc_fp8x8(v, a);
        }
    }
#pragma unroll
    for (int j = 0; j < 8; ++j) a[j] += b2[j];
#pragma unroll
    for (int j = 0; j < 8; ++j) a[j] += __shfl_xor(a[j], 16);
#pragma unroll
    for (int j = 0; j < 8; ++j) a[j] += __shfl_xor(a[j], 32);

    if (g == 0) {
        float sf[8] = {0.f, 0.f, 0.f, 0.f, 0.f, 0.f, 0.f, 0.f};
        acc_fp8x8(selfu, sf);
        bf16x8 whi;
#pragma unroll
        for (int j = 0; j < 8; ++j) whi[j] = (__bf16)(a[j] + sf[j]);
        ((bf16x8*)ohi)[(size_t)node * 16 + c] = whi;
    }
}

// ===========================================================================
// Mid-layer GEMM: 64 rows x 128 cols, K=128, plain bf16 single-MFMA,
// stage-W-once (32KB), barrier-free k-loop. h output = FP8.
// ===========================================================================
__global__ __launch_bounds__(256) void gemm64(
    const __bf16* __restrict__ Ahi,
    const __bf16* __restrict__ Wthi,
    const float* __restrict__ bias, unsigned char* __restrict__ Ofp8, int M) {
    __shared__ __align__(16) char smem[34816];
    __bf16* sW = (__bf16*)smem;                  // 128 x 128 = 32KB

    int tid = threadIdx.x;
    int row0 = blockIdx.x * 64;
    int wave = tid >> 6;
    int l = tid & 63;
    int m16 = l & 15;
    int q = l >> 4;
    int garow = min(row0 + wave * 16 + m16, M - 1);

#pragma unroll
    for (int it = 0; it < 8; ++it) {
        int lin = it * 2048 + tid * 8;
        int wr = lin >> 7, k = lin & 127;
        int off = wr * 128 + (((k >> 3) ^ (wr & 7)) << 3);
        *(bf16x8*)(sW + off) = *(const bf16x8*)&Wthi[(size_t)wr * 128 + k];
    }
    __syncthreads();

    floatx4 acc[8];
#pragma unroll
    for (int t = 0; t < 8; ++t) acc[t] = (floatx4){0.f, 0.f, 0.f, 0.f};

#pragma unroll
    for (int fs = 0; fs < 4; ++fs) {
        int kk = fs * 32 + q * 8;
        bf16x8 a = *(const bf16x8*)&Ahi[(size_t)garow * 128 + kk];
#pragma unroll
        for (int t = 0; t < 8; ++t) {
            int n = t * 16 + m16;
            int soff = n * 128 + (((kk >> 3) ^ (n & 7)) << 3);
            bf16x8 b = *(bf16x8*)(sW + soff);
            acc[t] = __builtin_amdgcn_mfma_f32_16x16x32_bf16(a, b, acc[t], 0, 0, 0);
        }
    }

    __syncthreads();
    float* eps = (float*)smem;  // 64*132*4 = 33792 <= 34816
#pragma unroll
    for (int t = 0; t < 8; ++t) {
        int col = t * 16 + m16;
        float bb = bias[col];
#pragma unroll
        for (int i = 0; i < 4; ++i) {
            int row = wave * 16 + q * 4 + i;
            eps[row * 132 + col] = fmaxf(acc[t][i] + bb, 0.f);
        }
    }
    __syncthreads();
#pragma unroll
    for (int it = 0; it < 8; ++it) {
        int lin = it * 1024 + tid * 4;
        int row = lin >> 7, col = lin & 127;
        int g = row0 + row;
        if (g < M) {
            float4 v = *(float4*)(eps + row * 132 + col);
            unsigned int p = enc_e4m3(v.x) | (enc_e4m3(v.y) << 8) |
                             (enc_e4m3(v.z) << 16) | (enc_e4m3(v.w) << 24);
            *(unsigned int*)&Ofp8[(size_t)g * 128 + col] = p;
        }
    }
}

// ===========================================================================
// Final layer: plain-bf16 stage-W-once GEMM (64x128, K=128) + fused output
// layer + log_softmax. A = sum (bf16).
// ===========================================================================
__global__ __launch_bounds__(256) void gemm_out_once(
    const __bf16* __restrict__ Ahi,
    const __bf16* __restrict__ Wthi,
    const float* __restrict__ bias,
    const float* __restrict__ Wout, const float* __restrict__ bout,
    float* __restrict__ out, int M) {
    __shared__ __align__(16) char smem[57344];
    __bf16* sW = (__bf16*)smem;                  // 128 x 128 = 32KB

    int tid = threadIdx.x;
    int row0 = blockIdx.x * 64;
    int wave = tid >> 6;
    int l = tid & 63;
    int m16 = l & 15;
    int q = l >> 4;
    int garow = min(row0 + wave * 16 + m16, M - 1);

#pragma unroll
    for (int it = 0; it < 8; ++it) {
        int lin = it * 2048 + tid * 8;
        int wr = lin >> 7, k = lin & 127;
        int off = wr * 128 + (((k >> 3) ^ (wr & 7)) << 3);
        *(bf16x8*)(sW + off) = *(const bf16x8*)&Wthi[(size_t)wr * 128 + k];
    }
    __syncthreads();

    floatx4 acc[8];
#pragma unroll
    for (int t = 0; t < 8; ++t) acc[t] = (floatx4){0.f, 0.f, 0.f, 0.f};

#pragma unroll
    for (int fs = 0; fs < 4; ++fs) {
        int kk = fs * 32 + q * 8;
        bf16x8 a = *(const bf16x8*)&Ahi[(size_t)garow * 128 + kk];
#pragma unroll
        for (int t = 0; t < 8; ++t) {
            int n = t * 16 + m16;
            int soff = n * 128 + (((kk >> 3) ^ (n & 7)) << 3);
            bf16x8 b = *(bf16x8*)(sW + soff);
            acc[t] = __builtin_amdgcn_mfma_f32_16x16x32_bf16(a, b, acc[t], 0, 0, 0);
        }
    }

    __syncthreads();
    float* eps = (float*)smem;                    // 64*132*4 = 33792 B
    float* sWo = (float*)(smem + 34816);          // 128*40*4 = 20480 B
    float* sb  = (float*)(smem + 55296);          // 160 B
#pragma unroll
    for (int t = 0; t < 8; ++t) {
        int col = t * 16 + m16;
        float bb = bias[col];
#pragma unroll
        for (int i = 0; i < 4; ++i) {
            int row = wave * 16 + q * 4 + i;
            eps[row * 132 + col] = fmaxf(acc[t][i] + bb, 0.f);
        }
    }
    for (int i = tid; i < 128 * NCLASS; i += 256) sWo[i] = Wout[i];
    if (tid < NCLASS) sb[tid] = bout[tid];
    __syncthreads();

    int r = tid >> 2;
    int cg = tid & 3;
    float z[10];
#pragma unroll
    for (int j = 0; j < 10; ++j) z[j] = sb[cg * 10 + j];
    for (int k = 0; k < 128; ++k) {
        float a = eps[r * 132 + k];
#pragma unroll
        for (int j = 0; j < 10; ++j) z[j] += a * sWo[k * NCLASS + cg * 10 + j];
    }
    float m = z[0];
#pragma unroll
    for (int j = 1; j < 10; ++j) m = fmaxf(m, z[j]);
    m = fmaxf(m, __shfl_xor(m, 1));
    m = fmaxf(m, __shfl_xor(m, 2));
    float s = 0.f;
#pragma unroll
    for (int j = 0; j < 10; ++j) s += expf(z[j] - m);
    s += __shfl_xor(s, 1);
    s += __shfl_xor(s, 2);
    float lse = m + logf(s);
    int row = row0 + r;
    if (row < M) {
#pragma unroll
        for (int j = 0; j < 10; ++j) out[(size_t)row * NCLASS + cg * 10 + j] = z[j] - lse;
    }
}

// ===========================================================================
extern "C" void kernel_launch(void* const* d_in, const int* in_sizes, int n_in,
                              void* d_out, int out_size, void* d_ws, size_t ws_size,
                              hipStream_t stream) {
    const float* x      = (const float*)d_in[0];
    const int*   esrc   = (const int*)d_in[1];
    const int*   edst   = (const int*)d_in[2];
    const float* W_in   = (const float*)d_in[3];
    const float* b_in   = (const float*)d_in[4];
    const float* W_mlps = (const float*)d_in[5];
    const float* b_mlps = (const float*)d_in[6];
    const float* W_out  = (const float*)d_in[7];
    const float* b_out  = (const float*)d_in[8];
    float* out = (float*)d_out;

    int N = in_sizes[0] / NFEAT;  // 50000
    int E = in_sizes[1];          // 800000
    int nbuck = (N + 255) >> 8;   // 196

    // workspace carve
    char* ws = (char*)d_ws;
    size_t hb = (((size_t)N * NHID * sizeof(__bf16)) + 255) & ~(size_t)255;  // 12.8MB
    unsigned char* h_fp8_a = (unsigned char*)ws;            // 6.4MB used
    unsigned char* h_fp8_b = (unsigned char*)(ws + 2 * hb); // 6.4MB used
    __bf16* sum_hi = (__bf16*)(ws + 4 * hb);
    // bdata aliases sum_hi's slot: used only during CSR build
    unsigned int* bdata = (unsigned int*)(ws + 4 * hb);
    char* ip = ws + 6 * hb;
    int* row_ptr = (int*)ip;  ip += (((size_t)(N + 1) * 4) + 255) & ~(size_t)255;
    int* srcs    = (int*)ip;  ip += (((size_t)E * 4) + 255) & ~(size_t)255;
    int* bucket_counts = (int*)ip;  ip += 1024;
    int* bucket_start  = (int*)ip;  ip += 1024;
    int* bucket_cursor = (int*)ip;  ip += 1024;
    __bf16* Wt_in_hi   = (__bf16*)ip;  ip += 128 * NFEAT * 2;
    __bf16* Wt_mlps_hi = (__bf16*)ip;  ip += 3 * 128 * NHID * 2;

    int eb4 = (E + 4095) / 4096;  // 196
    int gb = (N + 63) / 64;       // 782

    // ---- CSR build + weight prep ----
    hipMemsetAsync(bucket_counts, 0, 1024, stream);
    hist_transpose<<<eb4 + 320, 256, 0, stream>>>(edst, bucket_counts, E, eb4, nbuck,
                                                  W_in, W_mlps, Wt_in_hi, Wt_mlps_hi);
    bucket_scan<<<1, 256, 0, stream>>>(bucket_counts, bucket_start, bucket_cursor,
                                       row_ptr, nbuck, E, N);
    bucket_scatter<<<eb4, 256, 0, stream>>>(esrc, edst, bucket_cursor, bdata, E, nbuck);
    // ---- finalize || input-layer GEMM (h -> fp8) ----
    fin_gemmin64<<<nbuck + gb, 256, 0, stream>>>(bdata, bucket_start, row_ptr, srcs,
                                                 N, nbuck, x, Wt_in_hi, b_in, h_fp8_a);

    // ---- GIN layers 0,1 ----
    unsigned char* cur = h_fp8_a;
    unsigned char* nxt = h_fp8_b;
    for (int i = 0; i < 2; ++i) {
        aggregate_fused<<<(N + 3) / 4, 256, 0, stream>>>(cur, row_ptr, srcs, sum_hi, N);
        gemm64<<<gb, 256, 0, stream>>>(
            sum_hi, Wt_mlps_hi + (size_t)i * 128 * NHID,
            b_mlps + (size_t)i * NHID, nxt, N);
        unsigned char* t = cur; cur = nxt; nxt = t;
    }

    // ---- GIN layer 2 fused with output layer + log_softmax ----
    aggregate_fused<<<(N + 3) / 4, 256, 0, stream>>>(cur, row_ptr, srcs, sum_hi, N);
    gemm_out_once<<<gb, 256, 0, stream>>>(sum_hi,
                                          Wt_mlps_hi + (size_t)2 * 128 * NHID,
                                          b_mlps + (size_t)2 * NHID,
                                          W_out, b_out, out, N);
}

// Round 16
// 284.831 us; speedup vs baseline: 1.2067x; 1.2067x over previous
//
#include <hip/hip_runtime.h>
#include <math.h>

#define NHID 128
#define NFEAT 256
#define NCLASS 40

typedef __bf16 bf16x8 __attribute__((ext_vector_type(8)));
typedef __bf16 bf16x4 __attribute__((ext_vector_type(4)));
typedef float floatx4 __attribute__((ext_vector_type(4)));

// ===========================================================================
// CSR build via 2-level bucketed counting sort.
// Bucket = dst >> 8; record = (dst&255)<<16 | src  (N <= 65536).
// Dispatch A: hist (blocks [0,eb4)) || weight transpose (blocks [eb4,eb4+320)).
// Weights are bf16 single precision (r13-validated).
// ===========================================================================
__global__ __launch_bounds__(256) void hist_transpose(
    const int* __restrict__ edst, int* __restrict__ bucket_counts, int E, int eb4,
    int nbuck,
    const float* __restrict__ Win, const float* __restrict__ Wmlps,
    __bf16* __restrict__ dInHi, __bf16* __restrict__ dMlHi) {
    __shared__ int lh[256];
    int tid = threadIdx.x;
    int bid = blockIdx.x;
    if (bid < eb4) {
        lh[tid] = 0;
        __syncthreads();
        int base = bid * 4096;
#pragma unroll
        for (int k = 0; k < 16; ++k) {
            int e = base + k * 256 + tid;
            if (e < E) atomicAdd(&lh[edst[e] >> 8], 1);
        }
        __syncthreads();
        if (tid < nbuck && lh[tid]) atomicAdd(&bucket_counts[tid], lh[tid]);
    } else {
        const int TOT_IN = 128 * NFEAT;      // 32768
        const int TOT_ML = 3 * 128 * NHID;   // 49152
        int i = (bid - eb4) * 256 + tid;
        if (i < TOT_IN) {
            int n = i / NFEAT;
            int k = i - n * NFEAT;
            dInHi[i] = (__bf16)Win[(size_t)k * 128 + n];
        } else if (i < TOT_IN + TOT_ML) {
            int r = i - TOT_IN;
            int per = 128 * NHID;
            int l = r / per;
            int rr = r - l * per;
            int n = rr / NHID;
            int k = rr - n * NHID;
            dMlHi[r] = (__bf16)Wmlps[(size_t)l * per + (size_t)k * 128 + n];
        }
    }
}

__global__ __launch_bounds__(256) void bucket_scan(const int* __restrict__ counts,
                                                   int* __restrict__ start,
                                                   int* __restrict__ cursor,
                                                   int* __restrict__ row_ptr,
                                                   int nbuck, int E, int N) {
    __shared__ int lds[256];
    int tid = threadIdx.x;
    int v = (tid < nbuck) ? counts[tid] : 0;
    lds[tid] = v;
    __syncthreads();
    for (int off = 1; off < 256; off <<= 1) {
        int t = (tid >= off) ? lds[tid - off] : 0;
        __syncthreads();
        lds[tid] += t;
        __syncthreads();
    }
    int excl = lds[tid] - v;
    if (tid < nbuck) { start[tid] = excl; cursor[tid] = excl; }
    if (tid == 0) { start[nbuck] = E; row_ptr[N] = E; }
}

__global__ __launch_bounds__(256) void bucket_scatter(const int* __restrict__ esrc,
                                                      const int* __restrict__ edst,
                                                      int* __restrict__ cursor,
                                                      unsigned int* __restrict__ bdata,
                                                      int E, int nbuck) {
    __shared__ int lh[256];
    __shared__ int lbase[256];
    int tid = threadIdx.x;
    lh[tid] = 0;
    __syncthreads();
    int base = blockIdx.x * 4096;
    unsigned int recs[16];
    short bks[16];
    short lofs[16];
#pragma unroll
    for (int k = 0; k < 16; ++k) {
        int e = base + k * 256 + tid;
        bks[k] = -1;
        if (e < E) {
            int d = edst[e];
            int s = esrc[e];
            int b = d >> 8;
            recs[k] = ((unsigned int)(d & 255) << 16) | (unsigned int)s;
            bks[k] = (short)b;
            lofs[k] = (short)atomicAdd(&lh[b], 1);
        }
    }
    __syncthreads();
    if (tid < nbuck && lh[tid]) lbase[tid] = atomicAdd(&cursor[tid], lh[tid]);
    __syncthreads();
#pragma unroll
    for (int k = 0; k < 16; ++k) {
        if (bks[k] >= 0) bdata[lbase[bks[k]] + lofs[k]] = recs[k];
    }
}

// ===========================================================================
// Dispatch D: FINALIZE (blocks [0,nbuck)) || GEMM_IN (blocks [nbuck,..+gb)).
// gemm_in_full: 64 rows x FULL 128 cols, K=256. W bf16 single = 64KB staged
// once; x read ONCE; A keeps in-register fp32->hi/lo split (2 MFMA per
// fragment); barrier-free k-loop; h output hi-only bf16.
// ===========================================================================
__global__ __launch_bounds__(256) void fin_gemmin64(
    const unsigned int* __restrict__ bdata, const int* __restrict__ start,
    int* __restrict__ row_ptr, int* __restrict__ srcs, int N, int nbuck,
    const float* __restrict__ Af,
    const __bf16* __restrict__ Wthi,
    const float* __restrict__ bias, __bf16* __restrict__ Ohi) {
    __shared__ __align__(16) char smem[65536];
    int tid = threadIdx.x;
    if ((int)blockIdx.x < nbuck) {
        int* hist = (int*)smem;
        int* cur  = (int*)(smem + 1024);
        int b = blockIdx.x;
        int s0 = start[b];
        int cnt = start[b + 1] - s0;
        hist[tid] = 0;
        __syncthreads();
        for (int i = tid; i < cnt; i += 256) atomicAdd(&hist[bdata[s0 + i] >> 16], 1);
        __syncthreads();
        int v0 = hist[tid];
        __syncthreads();
        for (int off = 1; off < 256; off <<= 1) {
            int t = (tid >= off) ? hist[tid - off] : 0;
            __syncthreads();
            hist[tid] += t;
            __syncthreads();
        }
        int excl = hist[tid] - v0;
        cur[tid] = excl;
        int node = b * 256 + tid;
        if (node < N) row_ptr[node] = s0 + excl;
        __syncthreads();
        for (int i = tid; i < cnt; i += 256) {
            unsigned int r = bdata[s0 + i];
            int p = atomicAdd(&cur[r >> 16], 1);
            srcs[s0 + p] = (int)(r & 0xffffu);
        }
        return;
    }
    // ---------------- gemm_in_full ----------------
    __bf16* sW = (__bf16*)smem;                  // 128 cols x 256 k = 64KB
    int bix = (int)blockIdx.x - nbuck;
    int row0 = bix * 64;
    int wave = tid >> 6;
    int l = tid & 63;
    int m16 = l & 15;
    int q = l >> 4;
    int garow = min(row0 + wave * 16 + m16, N - 1);

    // stage W once
#pragma unroll
    for (int it = 0; it < 16; ++it) {
        int lin = it * 2048 + tid * 8;
        int wr = lin >> 8, k = lin & 255;
        int off = wr * 256 + (((k >> 3) ^ (wr & 7)) << 3);
        *(bf16x8*)(sW + off) = *(const bf16x8*)&Wthi[(size_t)wr * 256 + k];
    }
    __syncthreads();

    floatx4 acc[8];
#pragma unroll
    for (int t = 0; t < 8; ++t) acc[t] = (floatx4){0.f, 0.f, 0.f, 0.f};

    // barrier-free k-loop: 8 fragment-steps of 32 k
#pragma unroll
    for (int fs = 0; fs < 8; ++fs) {
        int kk = fs * 32 + q * 8;
        float4 v0 = *(const float4*)&Af[(size_t)garow * 256 + kk];
        float4 v1 = *(const float4*)&Af[(size_t)garow * 256 + kk + 4];
        float sv[8] = {v0.x, v0.y, v0.z, v0.w, v1.x, v1.y, v1.z, v1.w};
        bf16x8 ahi, alo;
#pragma unroll
        for (int j = 0; j < 8; ++j) {
            __bf16 h = (__bf16)sv[j];
            ahi[j] = h;
            alo[j] = (__bf16)(sv[j] - (float)h);
        }
#pragma unroll
        for (int t = 0; t < 8; ++t) {
            int n = t * 16 + m16;
            int soff = n * 256 + (((kk >> 3) ^ (n & 7)) << 3);
            bf16x8 b = *(bf16x8*)(sW + soff);
            acc[t] = __builtin_amdgcn_mfma_f32_16x16x32_bf16(ahi, b, acc[t], 0, 0, 0);
            acc[t] = __builtin_amdgcn_mfma_f32_16x16x32_bf16(alo, b, acc[t], 0, 0, 0);
        }
    }

    // epilogue: reuse W LDS as 64x132 fp32 buffer; hi-only bf16 store
    __syncthreads();
    float* eps = (float*)smem;
#pragma unroll
    for (int t = 0; t < 8; ++t) {
        int col = t * 16 + m16;
        float bb = bias[col];
#pragma unroll
        for (int i = 0; i < 4; ++i) {
            int row = wave * 16 + q * 4 + i;
            eps[row * 132 + col] = fmaxf(acc[t][i] + bb, 0.f);
        }
    }
    __syncthreads();
#pragma unroll
    for (int it = 0; it < 8; ++it) {
        int lin = it * 1024 + tid * 4;
        int row = lin >> 7, col = lin & 127;
        int g = row0 + row;
        if (g < N) {
            float4 v = *(float4*)(eps + row * 132 + col);
            bf16x4 hi;
            float vv[4] = {v.x, v.y, v.z, v.w};
#pragma unroll
            for (int j = 0; j < 4; ++j) hi[j] = (__bf16)vv[j];
            *(bf16x4*)&Ohi[(size_t)g * 128 + col] = hi;
        }
    }
}

// ===========================================================================
// Fused aggregate: sum = h[node] + sum_{src in CSR} h[src]  (h hi-only),
// written hi-only bf16. One wave/node; 16 lanes x 16B row; 16 edges
// (4 gathers) in flight.
// ===========================================================================
__global__ __launch_bounds__(256) void aggregate_fused(const __bf16* __restrict__ hhi,
                                                       const int* __restrict__ row_ptr,
                                                       const int* __restrict__ srcs,
                                                       __bf16* __restrict__ ohi, int N) {
    int tid = threadIdx.x;
    int node = blockIdx.x * 4 + (tid >> 6);
    if (node >= N) return;
    int lane = tid & 63;
    int g = lane >> 4;
    int c = lane & 15;
    int beg = row_ptr[node];
    int end = row_ptr[node + 1];
    const bf16x8* hv = (const bf16x8*)hhi;

    bf16x8 sh = hv[(size_t)node * 16 + c];

    float a[8], b2[8];
#pragma unroll
    for (int j = 0; j < 8; ++j) { a[j] = 0.f; b2[j] = 0.f; }

    int i = beg;
    for (; i + 16 <= end; i += 16) {
        int s0 = __builtin_nontemporal_load(&srcs[i + g]);
        int s1 = __builtin_nontemporal_load(&srcs[i + 4 + g]);
        int s2 = __builtin_nontemporal_load(&srcs[i + 8 + g]);
        int s3 = __builtin_nontemporal_load(&srcs[i + 12 + g]);
        bf16x8 v0 = hv[(size_t)s0 * 16 + c];
        bf16x8 v1 = hv[(size_t)s1 * 16 + c];
        bf16x8 v2 = hv[(size_t)s2 * 16 + c];
        bf16x8 v3 = hv[(size_t)s3 * 16 + c];
#pragma unroll
        for (int j = 0; j < 8; ++j) {
            a[j] += (float)v0[j] + (float)v2[j];
            b2[j] += (float)v1[j] + (float)v3[j];
        }
    }
    for (; i + 8 <= end; i += 8) {
        int s0 = __builtin_nontemporal_load(&srcs[i + g]);
        int s1 = __builtin_nontemporal_load(&srcs[i + 4 + g]);
        bf16x8 v0 = hv[(size_t)s0 * 16 + c];
        bf16x8 v1 = hv[(size_t)s1 * 16 + c];
#pragma unroll
        for (int j = 0; j < 8; ++j) { a[j] += (float)v0[j]; b2[j] += (float)v1[j]; }
    }
    for (; i < end; i += 4) {
        if (i + g < end) {
            int s = __builtin_nontemporal_load(&srcs[i + g]);
            bf16x8 v = hv[(size_t)s * 16 + c];
#pragma unroll
            for (int j = 0; j < 8; ++j) a[j] += (float)v[j];
        }
    }
#pragma unroll
    for (int j = 0; j < 8; ++j) a[j] += b2[j];
#pragma unroll
    for (int j = 0; j < 8; ++j) a[j] += __shfl_xor(a[j], 16);
#pragma unroll
    for (int j = 0; j < 8; ++j) a[j] += __shfl_xor(a[j], 32);

    if (g == 0) {
        bf16x8 whi;
#pragma unroll
        for (int j = 0; j < 8; ++j) whi[j] = (__bf16)(a[j] + (float)sh[j]);
        ((bf16x8*)ohi)[(size_t)node * 16 + c] = whi;
    }
}

// ===========================================================================
// Mid-layer GEMM: 64 rows x FULL 128 cols, K=128, plain bf16 single-MFMA.
// W = 32KB staged once; sum read ONCE; barrier-free k-loop; hi-only h out.
// ===========================================================================
__global__ __launch_bounds__(256) void gemm64(
    const __bf16* __restrict__ Ahi,
    const __bf16* __restrict__ Wthi,
    const float* __restrict__ bias, __bf16* __restrict__ Ohi, int M) {
    __shared__ __align__(16) char smem[34816];
    __bf16* sW = (__bf16*)smem;                  // 128 x 128 = 32KB

    int tid = threadIdx.x;
    int row0 = blockIdx.x * 64;
    int wave = tid >> 6;
    int l = tid & 63;
    int m16 = l & 15;
    int q = l >> 4;
    int garow = min(row0 + wave * 16 + m16, M - 1);

#pragma unroll
    for (int it = 0; it < 8; ++it) {
        int lin = it * 2048 + tid * 8;
        int wr = lin >> 7, k = lin & 127;
        int off = wr * 128 + (((k >> 3) ^ (wr & 7)) << 3);
        *(bf16x8*)(sW + off) = *(const bf16x8*)&Wthi[(size_t)wr * 128 + k];
    }
    __syncthreads();

    floatx4 acc[8];
#pragma unroll
    for (int t = 0; t < 8; ++t) acc[t] = (floatx4){0.f, 0.f, 0.f, 0.f};

#pragma unroll
    for (int fs = 0; fs < 4; ++fs) {
        int kk = fs * 32 + q * 8;
        bf16x8 a = *(const bf16x8*)&Ahi[(size_t)garow * 128 + kk];
#pragma unroll
        for (int t = 0; t < 8; ++t) {
            int n = t * 16 + m16;
            int soff = n * 128 + (((kk >> 3) ^ (n & 7)) << 3);
            bf16x8 b = *(bf16x8*)(sW + soff);
            acc[t] = __builtin_amdgcn_mfma_f32_16x16x32_bf16(a, b, acc[t], 0, 0, 0);
        }
    }

    __syncthreads();
    float* eps = (float*)smem;  // 64*132*4 = 33792 <= 34816
#pragma unroll
    for (int t = 0; t < 8; ++t) {
        int col = t * 16 + m16;
        float bb = bias[col];
#pragma unroll
        for (int i = 0; i < 4; ++i) {
            int row = wave * 16 + q * 4 + i;
            eps[row * 132 + col] = fmaxf(acc[t][i] + bb, 0.f);
        }
    }
    __syncthreads();
#pragma unroll
    for (int it = 0; it < 8; ++it) {
        int lin = it * 1024 + tid * 4;
        int row = lin >> 7, col = lin & 127;
        int g = row0 + row;
        if (g < M) {
            float4 v = *(float4*)(eps + row * 132 + col);
            bf16x4 hi;
            float vv[4] = {v.x, v.y, v.z, v.w};
#pragma unroll
            for (int j = 0; j < 4; ++j) hi[j] = (__bf16)vv[j];
            *(bf16x4*)&Ohi[(size_t)g * 128 + col] = hi;
        }
    }
}

// ===========================================================================
// Final layer: plain-bf16 stage-W-once GEMM (64x128, K=128) + fused output
// layer + log_softmax. A = sum hi-only.
// ===========================================================================
__global__ __launch_bounds__(256) void gemm_out_once(
    const __bf16* __restrict__ Ahi,
    const __bf16* __restrict__ Wthi,
    const float* __restrict__ bias,
    const float* __restrict__ Wout, const float* __restrict__ bout,
    float* __restrict__ out, int M) {
    __shared__ __align__(16) char smem[57344];
    __bf16* sW = (__bf16*)smem;                  // 128 x 128 = 32KB

    int tid = threadIdx.x;
    int row0 = blockIdx.x * 64;
    int wave = tid >> 6;
    int l = tid & 63;
    int m16 = l & 15;
    int q = l >> 4;
    int garow = min(row0 + wave * 16 + m16, M - 1);

#pragma unroll
    for (int it = 0; it < 8; ++it) {
        int lin = it * 2048 + tid * 8;
        int wr = lin >> 7, k = lin & 127;
        int off = wr * 128 + (((k >> 3) ^ (wr & 7)) << 3);
        *(bf16x8*)(sW + off) = *(const bf16x8*)&Wthi[(size_t)wr * 128 + k];
    }
    __syncthreads();

    floatx4 acc[8];
#pragma unroll
    for (int t = 0; t < 8; ++t) acc[t] = (floatx4){0.f, 0.f, 0.f, 0.f};

#pragma unroll
    for (int fs = 0; fs < 4; ++fs) {
        int kk = fs * 32 + q * 8;
        bf16x8 a = *(const bf16x8*)&Ahi[(size_t)garow * 128 + kk];
#pragma unroll
        for (int t = 0; t < 8; ++t) {
            int n = t * 16 + m16;
            int soff = n * 128 + (((kk >> 3) ^ (n & 7)) << 3);
            bf16x8 b = *(bf16x8*)(sW + soff);
            acc[t] = __builtin_amdgcn_mfma_f32_16x16x32_bf16(a, b, acc[t], 0, 0, 0);
        }
    }

    __syncthreads();
    float* eps = (float*)smem;                    // 64*132*4 = 33792 B
    float* sWo = (float*)(smem + 34816);          // 128*40*4 = 20480 B
    float* sb  = (float*)(smem + 55296);          // 160 B
#pragma unroll
    for (int t = 0; t < 8; ++t) {
        int col = t * 16 + m16;
        float bb = bias[col];
#pragma unroll
        for (int i = 0; i < 4; ++i) {
            int row = wave * 16 + q * 4 + i;
            eps[row * 132 + col] = fmaxf(acc[t][i] + bb, 0.f);
        }
    }
    for (int i = tid; i < 128 * NCLASS; i += 256) sWo[i] = Wout[i];
    if (tid < NCLASS) sb[tid] = bout[tid];
    __syncthreads();

    int r = tid >> 2;
    int cg = tid & 3;
    float z[10];
#pragma unroll
    for (int j = 0; j < 10; ++j) z[j] = sb[cg * 10 + j];
    for (int k = 0; k < 128; ++k) {
        float a = eps[r * 132 + k];
#pragma unroll
        for (int j = 0; j < 10; ++j) z[j] += a * sWo[k * NCLASS + cg * 10 + j];
    }
    float m = z[0];
#pragma unroll
    for (int j = 1; j < 10; ++j) m = fmaxf(m, z[j]);
    m = fmaxf(m, __shfl_xor(m, 1));
    m = fmaxf(m, __shfl_xor(m, 2));
    float s = 0.f;
#pragma unroll
    for (int j = 0; j < 10; ++j) s += expf(z[j] - m);
    s += __shfl_xor(s, 1);
    s += __shfl_xor(s, 2);
    float lse = m + logf(s);
    int row = row0 + r;
    if (row < M) {
#pragma unroll
        for (int j = 0; j < 10; ++j) out[(size_t)row * NCLASS + cg * 10 + j] = z[j] - lse;
    }
}

// ===========================================================================
extern "C" void kernel_launch(void* const* d_in, const int* in_sizes, int n_in,
                              void* d_out, int out_size, void* d_ws, size_t ws_size,
                              hipStream_t stream) {
    const float* x      = (const float*)d_in[0];
    const int*   esrc   = (const int*)d_in[1];
    const int*   edst   = (const int*)d_in[2];
    const float* W_in   = (const float*)d_in[3];
    const float* b_in   = (const float*)d_in[4];
    const float* W_mlps = (const float*)d_in[5];
    const float* b_mlps = (const float*)d_in[6];
    const float* W_out  = (const float*)d_in[7];
    const float* b_out  = (const float*)d_in[8];
    float* out = (float*)d_out;

    int N = in_sizes[0] / NFEAT;  // 50000
    int E = in_sizes[1];          // 800000
    int nbuck = (N + 255) >> 8;   // 196

    // workspace carve
    char* ws = (char*)d_ws;
    size_t hb = (((size_t)N * NHID * sizeof(__bf16)) + 255) & ~(size_t)255;  // 12.8MB
    __bf16* h_hi_a = (__bf16*)ws;
    __bf16* h_hi_b = (__bf16*)(ws + 2 * hb);
    __bf16* sum_hi = (__bf16*)(ws + 4 * hb);
    // bdata aliases sum_hi's slot: used only during CSR build
    unsigned int* bdata = (unsigned int*)(ws + 4 * hb);
    char* ip = ws + 6 * hb;
    int* row_ptr = (int*)ip;  ip += (((size_t)(N + 1) * 4) + 255) & ~(size_t)255;
    int* srcs    = (int*)ip;  ip += (((size_t)E * 4) + 255) & ~(size_t)255;
    int* bucket_counts = (int*)ip;  ip += 1024;
    int* bucket_start  = (int*)ip;  ip += 1024;
    int* bucket_cursor = (int*)ip;  ip += 1024;
    __bf16* Wt_in_hi   = (__bf16*)ip;  ip += 128 * NFEAT * 2;
    __bf16* Wt_mlps_hi = (__bf16*)ip;  ip += 3 * 128 * NHID * 2;

    int eb4 = (E + 4095) / 4096;  // 196
    int gb = (N + 63) / 64;       // 782

    // ---- CSR build + weight prep ----
    hipMemsetAsync(bucket_counts, 0, 1024, stream);
    hist_transpose<<<eb4 + 320, 256, 0, stream>>>(edst, bucket_counts, E, eb4, nbuck,
                                                  W_in, W_mlps, Wt_in_hi, Wt_mlps_hi);
    bucket_scan<<<1, 256, 0, stream>>>(bucket_counts, bucket_start, bucket_cursor,
                                       row_ptr, nbuck, E, N);
    bucket_scatter<<<eb4, 256, 0, stream>>>(esrc, edst, bucket_cursor, bdata, E, nbuck);
    // ---- finalize || input-layer GEMM (x read once, W bf16) ----
    fin_gemmin64<<<nbuck + gb, 256, 0, stream>>>(bdata, bucket_start, row_ptr, srcs,
                                                 N, nbuck, x, Wt_in_hi, b_in, h_hi_a);

    // ---- GIN layers 0,1 ----
    __bf16* cur_hi = h_hi_a;
    __bf16* nxt_hi = h_hi_b;
    for (int i = 0; i < 2; ++i) {
        aggregate_fused<<<(N + 3) / 4, 256, 0, stream>>>(cur_hi, row_ptr, srcs,
                                                         sum_hi, N);
        gemm64<<<gb, 256, 0, stream>>>(
            sum_hi, Wt_mlps_hi + (size_t)i * 128 * NHID,
            b_mlps + (size_t)i * NHID, nxt_hi, N);
        __bf16* t = cur_hi; cur_hi = nxt_hi; nxt_hi = t;
    }

    // ---- GIN layer 2 fused with output layer + log_softmax ----
    aggregate_fused<<<(N + 3) / 4, 256, 0, stream>>>(cur_hi, row_ptr, srcs,
                                                     sum_hi, N);
    gemm_out_once<<<gb, 256, 0, stream>>>(sum_hi,
                                          Wt_mlps_hi + (size_t)2 * 128 * NHID,
                                          b_mlps + (size_t)2 * NHID,
                                          W_out, b_out, out, N);
}